// Round 8
// baseline (7255.711 us; speedup 1.0000x reference)
//
#include <hip/hip_runtime.h>
#include <hip/hip_bf16.h>

// ConvGRU: fully fused cell kernels (2 dispatches per timestep).
// Each WG owns a 4x32 interior tile. It computes the GATES over the 6x34
// ring-extended region (halo-redundant) so r*h and z stay in LDS, then the
// CANDIDATE conv + GRU update locally. States fp16 NHWC with 2-px zero halo,
// double-buffered: S[B][134][134][32] per plane (h0 a/b, h1 a/b).
// LDS slots use octet rotation: ch-octet o of pixel p lives at part
// (o + (p>>2)) & 3  -> DMA-compatible, conflict-light for b128 + scalar reads.
// fp16 MFMA 16x16x32, fp32 acc (absmax ~1e-3 vs threshold 3.36e-3).

#define HH 128
#define PH2 134
#define HW 16384
#define BB 8
#define TT 16

typedef _Float16 f16x8 __attribute__((ext_vector_type(8)));
typedef float f32x4 __attribute__((ext_vector_type(4)));
typedef unsigned int u32x4 __attribute__((ext_vector_type(4)));

__device__ __forceinline__ unsigned short f2h(float x){
    return __builtin_bit_cast(unsigned short, (_Float16)x);
}
__device__ __forceinline__ float h2f(unsigned short u){
    return (float)__builtin_bit_cast(_Float16, u);
}
__device__ __forceinline__ f16x8 ld_frag(const unsigned short* p){
    u32x4 v = *(const u32x4*)p;
    return __builtin_bit_cast(f16x8, v);
}
// rotated-slot fragment read: pixel p, channel octet q
__device__ __forceinline__ f16x8 frag_rot(const unsigned short* s, int p, int q){
    u32x4 v = *(const u32x4*)(s + p * 32 + (((q + (p >> 2)) & 3) * 8));
    return __builtin_bit_cast(f16x8, v);
}
__device__ __forceinline__ float lds_scalar(const unsigned short* s, int p, int n){
    return h2f(s[p * 32 + ((((n >> 3) + (p >> 2)) & 3) * 8) + (n & 7)]);
}
__device__ __forceinline__ void lds_scalar_w(unsigned short* s, int p, int n, float v){
    s[p * 32 + ((((n >> 3) + (p >> 2)) & 3) * 8) + (n & 7)] = f2h(v);
}
__device__ __forceinline__ float sigmoid_f(float a){ return 1.0f / (1.0f + __expf(-a)); }
__device__ __forceinline__ float tanh_f(float a){ float e2 = __expf(2.0f * a); return 1.0f - 2.0f / (e2 + 1.0f); }

// DMA-stage one 8x36 (2-halo) 32-ch fp16 plane tile into a rotated LDS slot.
// 288 px * 4 parts = 1152 chunks of 16B; 18 wave-iters over 8 waves.
__device__ __forceinline__ void stage_slot(unsigned short* slot,
    const unsigned short* __restrict__ g, int pbase2, int wv)
{
    const int lane = threadIdx.x & 63;
    for (int k = wv; k < 18; k += 8) {
        int chunk = k * 64 + lane;
        int p = chunk >> 2, j = chunk & 3;
        int o = (j - (p >> 2)) & 3;            // content octet for this part
        int r = p / 36, c = p - r * 36;
        const unsigned short* ga = g + ((long)(pbase2 + r * PH2 + c) * 32 + o * 8);
        __builtin_amdgcn_global_load_lds(
            (const __attribute__((address_space(1))) unsigned int*)ga,
            (__attribute__((address_space(3))) unsigned int*)(slot + k * 512),
            16, 0, 0);
    }
}

// ---- weight prep: [cout][cin_tot][9] fp32 -> [step][cout][32] fp16 ----
__global__ void prep_w(const float* __restrict__ w, unsigned short* __restrict__ wf,
                       int CO, int CIT, int NSTEP, int xmode)
{
    int idx = blockIdx.x * 256 + threadIdx.x;
    int total = NSTEP * CO * 32;
    if (idx >= total) return;
    int kk = idx & 31;
    int t  = idx >> 5;
    int co = t % CO;
    int s  = t / CO;
    float v = 0.0f;
    if (xmode && s == NSTEP - 1) {
        if (kk < 9) v = w[(co * CIT + 0) * 9 + kk];
    } else {
        int tap = s % 9;
        int cin = (s / 9) * 32 + kk + (xmode ? 1 : 0);
        v = w[(co * CIT + cin) * 9 + tap];
    }
    wf[idx] = f2h(v);
}

// ---- fused GRU cell. LAYER 0: inputs x (im2col) + h0. LAYER 1: h0 + h1. ----
// 512 thr (8 waves). Gates: 13 m-tiles over the 6x34 region (transient acc);
// cand: 8 m-tiles (1/wave) over 4x32 interior. One kernel = whole cell.
template<int LAYER>
__global__ __launch_bounds__(512, 4)
void cell_kernel(const unsigned short* __restrict__ PA,   // L0: h0_prev, L1: h0_new
                 const unsigned short* __restrict__ PB,   // L1: h1_prev
                 unsigned short* __restrict__ Sout,       // h_new plane
                 const float* __restrict__ xraw, long xbs,
                 const unsigned short* __restrict__ Wg,
                 const unsigned short* __restrict__ Wc,
                 const float* __restrict__ bg, const float* __restrict__ bc)
{
    constexpr bool L0 = (LAYER == 0);
    constexpr int NSLOT = L0 ? 1 : 2;
    __shared__ __align__(16) unsigned short slot[NSLOT][9216];  // 8x36 x 32ch
    __shared__ __align__(16) unsigned short rhs[6528];          // 6x34 x 32ch (rotated)
    __shared__ __align__(16) unsigned short zs[4096];           // 4x32 x 32ch (plain; reused as h_new bounce)
    __shared__ unsigned short xs[L0 ? 296 : 2];                 // 8x37 fp16 (L0)

    const int b = blockIdx.y;
    const int tc = blockIdx.x & 3, tr = blockIdx.x >> 2;
    const int row0 = tr * 4, col0 = tc * 32;             // interior image origin
    const int pbase2 = (b * PH2 + row0) * PH2 + col0;    // staged (2-halo) origin

    const int wv = threadIdx.x >> 6, lane = threadIdx.x & 63;
    const int m = lane & 15, q = lane >> 4;

    stage_slot(slot[0], PA, pbase2, wv);
    if (!L0) stage_slot(slot[1], PB, pbase2, wv);
    if (L0) {
        const float* xb = xraw + (long)b * xbs;
        for (int p = threadIdx.x; p < 296; p += 512) {
            int r = p / 37, c = p - r * 37;
            int ir = row0 + r - 2, ic = col0 + c - 2;
            float v = 0.0f;
            if (c < 36 && ir >= 0 && ir < HH && ic >= 0 && ic < HH) v = xb[ir * HH + ic];
            xs[p] = f2h(v);
        }
    }
    __syncthreads();

    // ---------------- GATES over 6x34 region (13 m-tiles) ----------------
    for (int mt = wv; mt < 13; mt += 8) {
        int g = 16 * mt + m; g = g > 203 ? 203 : g;      // clamp A rows (dups OK)
        int gr = g / 34, gc = g - gr * 34;
        f32x4 acc[4];
#pragma unroll
        for (int ng = 0; ng < 4; ++ng) { float bv = bg[ng * 16 + m]; acc[ng] = f32x4{bv, bv, bv, bv}; }
#pragma unroll
        for (int s = 0; s < 9; ++s) {
            int ps = (gr + s / 3) * 36 + gc + s % 3;
            f16x8 A = frag_rot(slot[0], ps, q);
#pragma unroll
            for (int ng = 0; ng < 4; ++ng) {
                f16x8 B = ld_frag(Wg + (s * 64 + ng * 16 + m) * 32 + q * 8);
                acc[ng] = __builtin_amdgcn_mfma_f32_16x16x32_f16(A, B, acc[ng], 0, 0, 0);
            }
        }
        if (L0) {
            f16x8 A;
#pragma unroll
            for (int j = 0; j < 8; ++j) {
                int k = q * 8 + j;
                unsigned short xv = 0;
                if (k < 9) xv = xs[(gr + k / 3) * 37 + gc + k % 3];
                A[j] = __builtin_bit_cast(_Float16, xv);
            }
#pragma unroll
            for (int ng = 0; ng < 4; ++ng) {
                f16x8 B = ld_frag(Wg + (9 * 64 + ng * 16 + m) * 32 + q * 8);
                acc[ng] = __builtin_amdgcn_mfma_f32_16x16x32_f16(A, B, acc[ng], 0, 0, 0);
            }
        } else {
#pragma unroll
            for (int s = 9; s < 18; ++s) {
                int t2 = s - 9;
                int ps = (gr + t2 / 3) * 36 + gc + t2 % 3;
                f16x8 A = frag_rot(slot[1], ps, q);
#pragma unroll
                for (int ng = 0; ng < 4; ++ng) {
                    f16x8 B = ld_frag(Wg + (s * 64 + ng * 16 + m) * 32 + q * 8);
                    acc[ng] = __builtin_amdgcn_mfma_f32_16x16x32_f16(A, B, acc[ng], 0, 0, 0);
                }
            }
        }
        // epilogue: r*h -> rhs (rotated), z -> zs (interior only, plain)
        const unsigned short* hs = L0 ? slot[0] : slot[1];
#pragma unroll
        for (int ng = 0; ng < 2; ++ng)
#pragma unroll
            for (int rg = 0; rg < 4; ++rg) {
                int ge = 16 * mt + q * 4 + rg;
                if (ge > 203) continue;
                int n = ng * 16 + m;
                float rv = sigmoid_f(acc[ng][rg]);
                float zv = sigmoid_f(acc[ng + 2][rg]);
                int egr = ge / 34, egc = ge - egr * 34;
                int ps = (egr + 1) * 36 + egc + 1;       // gate px in staged frame
                float h = lds_scalar(hs, ps, n);
                lds_scalar_w(rhs, ge, n, rv * h);
                if (egr >= 1 && egr <= 4 && egc >= 1 && egc <= 32)
                    zs[((egr - 1) * 32 + egc - 1) * 32 + n] = f2h(zv);
            }
    }
    __syncthreads();

    // ---------------- CANDIDATE over 4x32 interior (1 m-tile / wave) -----
    {
        int i = 16 * wv + m;                 // 0..127
        int ir = i >> 5, ic = i & 31;
        f32x4 acc[2];
#pragma unroll
        for (int ng = 0; ng < 2; ++ng) { float bv = bc[ng * 16 + m]; acc[ng] = f32x4{bv, bv, bv, bv}; }
        if (L0) {
#pragma unroll
            for (int s = 0; s < 9; ++s) {    // r*h taps
                int p = (ir + s / 3) * 34 + ic + s % 3;
                f16x8 A = frag_rot(rhs, p, q);
#pragma unroll
                for (int ng = 0; ng < 2; ++ng) {
                    f16x8 B = ld_frag(Wc + (s * 32 + ng * 16 + m) * 32 + q * 8);
                    acc[ng] = __builtin_amdgcn_mfma_f32_16x16x32_f16(A, B, acc[ng], 0, 0, 0);
                }
            }
            f16x8 A;                          // x im2col step (s=9)
#pragma unroll
            for (int j = 0; j < 8; ++j) {
                int k = q * 8 + j;
                unsigned short xv = 0;
                if (k < 9) xv = xs[(ir + 1 + k / 3) * 37 + ic + 1 + k % 3];
                A[j] = __builtin_bit_cast(_Float16, xv);
            }
#pragma unroll
            for (int ng = 0; ng < 2; ++ng) {
                f16x8 B = ld_frag(Wc + (9 * 32 + ng * 16 + m) * 32 + q * 8);
                acc[ng] = __builtin_amdgcn_mfma_f32_16x16x32_f16(A, B, acc[ng], 0, 0, 0);
            }
        } else {
#pragma unroll
            for (int s = 0; s < 9; ++s) {    // h0 taps from slot0
                int ps = (ir + 1 + s / 3) * 36 + ic + 1 + s % 3;
                f16x8 A = frag_rot(slot[0], ps, q);
#pragma unroll
                for (int ng = 0; ng < 2; ++ng) {
                    f16x8 B = ld_frag(Wc + (s * 32 + ng * 16 + m) * 32 + q * 8);
                    acc[ng] = __builtin_amdgcn_mfma_f32_16x16x32_f16(A, B, acc[ng], 0, 0, 0);
                }
            }
#pragma unroll
            for (int s = 9; s < 18; ++s) {   // r*h1 taps
                int t2 = s - 9;
                int p = (ir + t2 / 3) * 34 + ic + t2 % 3;
                f16x8 A = frag_rot(rhs, p, q);
#pragma unroll
                for (int ng = 0; ng < 2; ++ng) {
                    f16x8 B = ld_frag(Wc + (s * 32 + ng * 16 + m) * 32 + q * 8);
                    acc[ng] = __builtin_amdgcn_mfma_f32_16x16x32_f16(A, B, acc[ng], 0, 0, 0);
                }
            }
        }
        // GRU update: h_new = (1-z)h + z*tanh(acc)
        const unsigned short* hs = L0 ? slot[0] : slot[NSLOT - 1];
        float hnew[2][4];
#pragma unroll
        for (int ng = 0; ng < 2; ++ng)
#pragma unroll
            for (int rg = 0; rg < 4; ++rg) {
                int i2 = 16 * wv + q * 4 + rg;
                int n = ng * 16 + m;
                float nv = tanh_f(acc[ng][rg]);
                float zz = h2f(zs[i2 * 32 + n]);
                int ps = ((i2 >> 5) + 2) * 36 + (i2 & 31) + 2;
                float h = lds_scalar(hs, ps, n);
                hnew[ng][rg] = (1.0f - zz) * h + zz * nv;
            }
        __syncthreads();
#pragma unroll
        for (int ng = 0; ng < 2; ++ng)
#pragma unroll
            for (int rg = 0; rg < 4; ++rg) {
                int i2 = 16 * wv + q * 4 + rg;
                int n = ng * 16 + m;
                zs[i2 * 32 + n] = f2h(hnew[ng][rg]);     // bounce (plain NHWC)
            }
        __syncthreads();
        // coalesced store of the 4x32x32 tile
        int off = threadIdx.x * 8;                       // 512*8 = 4096 exact
        int px = off >> 5, w = off & 31;
        int pg = (b * PH2 + row0 + (px >> 5) + 2) * PH2 + col0 + (px & 31) + 2;
        u32x4 v = *(const u32x4*)(zs + off);
        *(u32x4*)(Sout + (long)pg * 32 + w) = v;
    }
}

// ---- final: h1 plane -> d_out NCHW fp32 ----
__global__ void final_out(const unsigned short* __restrict__ S1, float* __restrict__ out)
{
    int i = blockIdx.x * 256 + threadIdx.x;    // B*32*HW = 4194304
    if (i >= BB * 32 * HW) return;
    int pix = i & 16383;
    int t = i >> 14;
    int c = t & 31, b = t >> 5;
    int r = pix >> 7, cc = pix & 127;
    long pg = (long)(b * PH2 + r + 2) * PH2 + cc + 2;
    out[i] = h2f(S1[pg * 32 + c]);
}

extern "C" void kernel_launch(void* const* d_in, const int* in_sizes, int n_in,
                              void* d_out, int out_size, void* d_ws, size_t ws_size,
                              hipStream_t stream)
{
    const float* seq = (const float*)d_in[0];
    const float* gw0 = (const float*)d_in[1];
    const float* gb0 = (const float*)d_in[2];
    const float* cw0 = (const float*)d_in[3];
    const float* cb0 = (const float*)d_in[4];
    const float* gw1 = (const float*)d_in[5];
    const float* gb1 = (const float*)d_in[6];
    const float* cw1 = (const float*)d_in[7];
    const float* cb1 = (const float*)d_in[8];
    float* out = (float*)d_out;

    const size_t PL = (size_t)BB * PH2 * PH2 * 32;   // 4,596,736 fp16 / plane

    char* p = (char*)d_ws;
    unsigned short* S0a = (unsigned short*)p; p += PL * 2;
    unsigned short* S0b = (unsigned short*)p; p += PL * 2;
    unsigned short* S1a = (unsigned short*)p; p += PL * 2;
    unsigned short* S1b = (unsigned short*)p; p += PL * 2;
    unsigned short* WG0 = (unsigned short*)p; p += 20480 * 2;
    unsigned short* WC0 = (unsigned short*)p; p += 10240 * 2;
    unsigned short* WG1 = (unsigned short*)p; p += 36864 * 2;
    unsigned short* WC1 = (unsigned short*)p; p += 18432 * 2;

    // zero all 4 planes (states + 2-px halos must be 0; harness poisons ws)
    hipMemsetAsync(S0a, 0, 4 * PL * 2, stream);

    prep_w<<<(10 * 64 * 32 + 255) / 256, 256, 0, stream>>>(gw0, WG0, 64, 33, 10, 1);
    prep_w<<<(10 * 32 * 32 + 255) / 256, 256, 0, stream>>>(cw0, WC0, 32, 33, 10, 1);
    prep_w<<<(18 * 64 * 32 + 255) / 256, 256, 0, stream>>>(gw1, WG1, 64, 64, 18, 0);
    prep_w<<<(18 * 32 * 32 + 255) / 256, 256, 0, stream>>>(cw1, WC1, 32, 64, 18, 0);

    dim3 grid(128, BB), block(512);
    const long xbs = (long)TT * HW;
    unsigned short *h0r = S0a, *h0w = S0b, *h1r = S1a, *h1w = S1b;
    for (int t = 0; t < TT; ++t) {
        const float* xt = seq + (long)t * HW;
        cell_kernel<0><<<grid, block, 0, stream>>>(h0r, h0r, h0w, xt, xbs, WG0, WC0, gb0, cb0);
        cell_kernel<1><<<grid, block, 0, stream>>>(h0w, h1r, h1w, xt, xbs, WG1, WC1, gb1, cb1);
        unsigned short* tmp;
        tmp = h0r; h0r = h0w; h0w = tmp;
        tmp = h1r; h1r = h1w; h1w = tmp;
    }
    final_out<<<(BB * 32 * HW + 255) / 256, 256, 0, stream>>>(h1r, out);
}

// Round 9
// 2049.306 us; speedup vs baseline: 3.5406x; 3.5406x over previous
//
#include <hip/hip_runtime.h>
#include <hip/hip_bf16.h>

// ConvGRU: fully fused cell kernels (2 dispatches per timestep).
// Each WG owns a 4x32 interior tile. It computes the GATES over the 6x34
// ring-extended region (halo-redundant) so r*h and z stay in LDS, then the
// CANDIDATE conv + GRU update locally. States fp16 NHWC with 2-px zero halo,
// double-buffered: S[B][134][134][32] per plane (h0 a/b, h1 a/b).
// LDS slots use octet rotation: ch-octet o of pixel p lives at part
// (o + (p>>2)) & 3  -> DMA-compatible, conflict-light for b128 + scalar reads.
// fp16 MFMA 16x16x32, fp32 acc (absmax ~1e-3 vs threshold 3.36e-3).
// R9: launch_bounds (512,2) [VGPR cap 256, kill scratch spill] + unroll 3
// on K-loops to bound live fragment loads.

#define HH 128
#define PH2 134
#define HW 16384
#define BB 8
#define TT 16

typedef _Float16 f16x8 __attribute__((ext_vector_type(8)));
typedef float f32x4 __attribute__((ext_vector_type(4)));
typedef unsigned int u32x4 __attribute__((ext_vector_type(4)));

__device__ __forceinline__ unsigned short f2h(float x){
    return __builtin_bit_cast(unsigned short, (_Float16)x);
}
__device__ __forceinline__ float h2f(unsigned short u){
    return (float)__builtin_bit_cast(_Float16, u);
}
__device__ __forceinline__ f16x8 ld_frag(const unsigned short* p){
    u32x4 v = *(const u32x4*)p;
    return __builtin_bit_cast(f16x8, v);
}
// rotated-slot fragment read: pixel p, channel octet q
__device__ __forceinline__ f16x8 frag_rot(const unsigned short* s, int p, int q){
    u32x4 v = *(const u32x4*)(s + p * 32 + (((q + (p >> 2)) & 3) * 8));
    return __builtin_bit_cast(f16x8, v);
}
__device__ __forceinline__ float lds_scalar(const unsigned short* s, int p, int n){
    return h2f(s[p * 32 + ((((n >> 3) + (p >> 2)) & 3) * 8) + (n & 7)]);
}
__device__ __forceinline__ void lds_scalar_w(unsigned short* s, int p, int n, float v){
    s[p * 32 + ((((n >> 3) + (p >> 2)) & 3) * 8) + (n & 7)] = f2h(v);
}
__device__ __forceinline__ float sigmoid_f(float a){ return 1.0f / (1.0f + __expf(-a)); }
__device__ __forceinline__ float tanh_f(float a){ float e2 = __expf(2.0f * a); return 1.0f - 2.0f / (e2 + 1.0f); }

// DMA-stage one 8x36 (2-halo) 32-ch fp16 plane tile into a rotated LDS slot.
// 288 px * 4 parts = 1152 chunks of 16B; 18 wave-iters over 8 waves.
__device__ __forceinline__ void stage_slot(unsigned short* slot,
    const unsigned short* __restrict__ g, int pbase2, int wv)
{
    const int lane = threadIdx.x & 63;
    for (int k = wv; k < 18; k += 8) {
        int chunk = k * 64 + lane;
        int p = chunk >> 2, j = chunk & 3;
        int o = (j - (p >> 2)) & 3;            // content octet for this part
        int r = p / 36, c = p - r * 36;
        const unsigned short* ga = g + ((long)(pbase2 + r * PH2 + c) * 32 + o * 8);
        __builtin_amdgcn_global_load_lds(
            (const __attribute__((address_space(1))) unsigned int*)ga,
            (__attribute__((address_space(3))) unsigned int*)(slot + k * 512),
            16, 0, 0);
    }
}

// ---- weight prep: [cout][cin_tot][9] fp32 -> [step][cout][32] fp16 ----
__global__ void prep_w(const float* __restrict__ w, unsigned short* __restrict__ wf,
                       int CO, int CIT, int NSTEP, int xmode)
{
    int idx = blockIdx.x * 256 + threadIdx.x;
    int total = NSTEP * CO * 32;
    if (idx >= total) return;
    int kk = idx & 31;
    int t  = idx >> 5;
    int co = t % CO;
    int s  = t / CO;
    float v = 0.0f;
    if (xmode && s == NSTEP - 1) {
        if (kk < 9) v = w[(co * CIT + 0) * 9 + kk];
    } else {
        int tap = s % 9;
        int cin = (s / 9) * 32 + kk + (xmode ? 1 : 0);
        v = w[(co * CIT + cin) * 9 + tap];
    }
    wf[idx] = f2h(v);
}

// ---- fused GRU cell. LAYER 0: inputs x (im2col) + h0. LAYER 1: h0 + h1. ----
// 512 thr (8 waves). Gates: 13 m-tiles over the 6x34 region (transient acc);
// cand: 8 m-tiles (1/wave) over 4x32 interior. One kernel = whole cell.
template<int LAYER>
__global__ __launch_bounds__(512, 2)
void cell_kernel(const unsigned short* __restrict__ PA,   // L0: h0_prev, L1: h0_new
                 const unsigned short* __restrict__ PB,   // L1: h1_prev
                 unsigned short* __restrict__ Sout,       // h_new plane
                 const float* __restrict__ xraw, long xbs,
                 const unsigned short* __restrict__ Wg,
                 const unsigned short* __restrict__ Wc,
                 const float* __restrict__ bg, const float* __restrict__ bc)
{
    constexpr bool L0 = (LAYER == 0);
    constexpr int NSLOT = L0 ? 1 : 2;
    __shared__ __align__(16) unsigned short slot[NSLOT][9216];  // 8x36 x 32ch
    __shared__ __align__(16) unsigned short rhs[6528];          // 6x34 x 32ch (rotated)
    __shared__ __align__(16) unsigned short zs[4096];           // 4x32 x 32ch (plain; reused as h_new bounce)
    __shared__ unsigned short xs[L0 ? 296 : 2];                 // 8x37 fp16 (L0)

    const int b = blockIdx.y;
    const int tc = blockIdx.x & 3, tr = blockIdx.x >> 2;
    const int row0 = tr * 4, col0 = tc * 32;             // interior image origin
    const int pbase2 = (b * PH2 + row0) * PH2 + col0;    // staged (2-halo) origin

    const int wv = threadIdx.x >> 6, lane = threadIdx.x & 63;
    const int m = lane & 15, q = lane >> 4;

    stage_slot(slot[0], PA, pbase2, wv);
    if (!L0) stage_slot(slot[1], PB, pbase2, wv);
    if (L0) {
        const float* xb = xraw + (long)b * xbs;
        for (int p = threadIdx.x; p < 296; p += 512) {
            int r = p / 37, c = p - r * 37;
            int ir = row0 + r - 2, ic = col0 + c - 2;
            float v = 0.0f;
            if (c < 36 && ir >= 0 && ir < HH && ic >= 0 && ic < HH) v = xb[ir * HH + ic];
            xs[p] = f2h(v);
        }
    }
    __syncthreads();

    // ---------------- GATES over 6x34 region (13 m-tiles) ----------------
    for (int mt = wv; mt < 13; mt += 8) {
        int g = 16 * mt + m; g = g > 203 ? 203 : g;      // clamp A rows (dups OK)
        int gr = g / 34, gc = g - gr * 34;
        f32x4 acc[4];
#pragma unroll
        for (int ng = 0; ng < 4; ++ng) { float bv = bg[ng * 16 + m]; acc[ng] = f32x4{bv, bv, bv, bv}; }
#pragma unroll 3
        for (int s = 0; s < 9; ++s) {
            int ps = (gr + s / 3) * 36 + gc + s % 3;
            f16x8 A = frag_rot(slot[0], ps, q);
#pragma unroll
            for (int ng = 0; ng < 4; ++ng) {
                f16x8 B = ld_frag(Wg + (s * 64 + ng * 16 + m) * 32 + q * 8);
                acc[ng] = __builtin_amdgcn_mfma_f32_16x16x32_f16(A, B, acc[ng], 0, 0, 0);
            }
        }
        if (L0) {
            f16x8 A;
#pragma unroll
            for (int j = 0; j < 8; ++j) {
                int k = q * 8 + j;
                unsigned short xv = 0;
                if (k < 9) xv = xs[(gr + k / 3) * 37 + gc + k % 3];
                A[j] = __builtin_bit_cast(_Float16, xv);
            }
#pragma unroll
            for (int ng = 0; ng < 4; ++ng) {
                f16x8 B = ld_frag(Wg + (9 * 64 + ng * 16 + m) * 32 + q * 8);
                acc[ng] = __builtin_amdgcn_mfma_f32_16x16x32_f16(A, B, acc[ng], 0, 0, 0);
            }
        } else {
#pragma unroll 3
            for (int s = 9; s < 18; ++s) {
                int t2 = s - 9;
                int ps = (gr + t2 / 3) * 36 + gc + t2 % 3;
                f16x8 A = frag_rot(slot[1], ps, q);
#pragma unroll
                for (int ng = 0; ng < 4; ++ng) {
                    f16x8 B = ld_frag(Wg + (s * 64 + ng * 16 + m) * 32 + q * 8);
                    acc[ng] = __builtin_amdgcn_mfma_f32_16x16x32_f16(A, B, acc[ng], 0, 0, 0);
                }
            }
        }
        // epilogue: r*h -> rhs (rotated), z -> zs (interior only, plain)
        const unsigned short* hs = L0 ? slot[0] : slot[1];
#pragma unroll
        for (int ng = 0; ng < 2; ++ng)
#pragma unroll
            for (int rg = 0; rg < 4; ++rg) {
                int ge = 16 * mt + q * 4 + rg;
                if (ge > 203) continue;
                int n = ng * 16 + m;
                float rv = sigmoid_f(acc[ng][rg]);
                float zv = sigmoid_f(acc[ng + 2][rg]);
                int egr = ge / 34, egc = ge - egr * 34;
                int ps = (egr + 1) * 36 + egc + 1;       // gate px in staged frame
                float h = lds_scalar(hs, ps, n);
                lds_scalar_w(rhs, ge, n, rv * h);
                if (egr >= 1 && egr <= 4 && egc >= 1 && egc <= 32)
                    zs[((egr - 1) * 32 + egc - 1) * 32 + n] = f2h(zv);
            }
    }
    __syncthreads();

    // ---------------- CANDIDATE over 4x32 interior (1 m-tile / wave) -----
    {
        int i = 16 * wv + m;                 // 0..127
        int ir = i >> 5, ic = i & 31;
        f32x4 acc[2];
#pragma unroll
        for (int ng = 0; ng < 2; ++ng) { float bv = bc[ng * 16 + m]; acc[ng] = f32x4{bv, bv, bv, bv}; }
        if (L0) {
#pragma unroll 3
            for (int s = 0; s < 9; ++s) {    // r*h taps
                int p = (ir + s / 3) * 34 + ic + s % 3;
                f16x8 A = frag_rot(rhs, p, q);
#pragma unroll
                for (int ng = 0; ng < 2; ++ng) {
                    f16x8 B = ld_frag(Wc + (s * 32 + ng * 16 + m) * 32 + q * 8);
                    acc[ng] = __builtin_amdgcn_mfma_f32_16x16x32_f16(A, B, acc[ng], 0, 0, 0);
                }
            }
            f16x8 A;                          // x im2col step (s=9)
#pragma unroll
            for (int j = 0; j < 8; ++j) {
                int k = q * 8 + j;
                unsigned short xv = 0;
                if (k < 9) xv = xs[(ir + 1 + k / 3) * 37 + ic + 1 + k % 3];
                A[j] = __builtin_bit_cast(_Float16, xv);
            }
#pragma unroll
            for (int ng = 0; ng < 2; ++ng) {
                f16x8 B = ld_frag(Wc + (9 * 32 + ng * 16 + m) * 32 + q * 8);
                acc[ng] = __builtin_amdgcn_mfma_f32_16x16x32_f16(A, B, acc[ng], 0, 0, 0);
            }
        } else {
#pragma unroll 3
            for (int s = 0; s < 9; ++s) {    // h0 taps from slot0
                int ps = (ir + 1 + s / 3) * 36 + ic + 1 + s % 3;
                f16x8 A = frag_rot(slot[0], ps, q);
#pragma unroll
                for (int ng = 0; ng < 2; ++ng) {
                    f16x8 B = ld_frag(Wc + (s * 32 + ng * 16 + m) * 32 + q * 8);
                    acc[ng] = __builtin_amdgcn_mfma_f32_16x16x32_f16(A, B, acc[ng], 0, 0, 0);
                }
            }
#pragma unroll 3
            for (int s = 9; s < 18; ++s) {   // r*h1 taps
                int t2 = s - 9;
                int p = (ir + t2 / 3) * 34 + ic + t2 % 3;
                f16x8 A = frag_rot(rhs, p, q);
#pragma unroll
                for (int ng = 0; ng < 2; ++ng) {
                    f16x8 B = ld_frag(Wc + (s * 32 + ng * 16 + m) * 32 + q * 8);
                    acc[ng] = __builtin_amdgcn_mfma_f32_16x16x32_f16(A, B, acc[ng], 0, 0, 0);
                }
            }
        }
        // GRU update: h_new = (1-z)h + z*tanh(acc)
        const unsigned short* hs = L0 ? slot[0] : slot[NSLOT - 1];
        float hnew[2][4];
#pragma unroll
        for (int ng = 0; ng < 2; ++ng)
#pragma unroll
            for (int rg = 0; rg < 4; ++rg) {
                int i2 = 16 * wv + q * 4 + rg;
                int n = ng * 16 + m;
                float nv = tanh_f(acc[ng][rg]);
                float zz = h2f(zs[i2 * 32 + n]);
                int ps = ((i2 >> 5) + 2) * 36 + (i2 & 31) + 2;
                float h = lds_scalar(hs, ps, n);
                hnew[ng][rg] = (1.0f - zz) * h + zz * nv;
            }
        __syncthreads();
#pragma unroll
        for (int ng = 0; ng < 2; ++ng)
#pragma unroll
            for (int rg = 0; rg < 4; ++rg) {
                int i2 = 16 * wv + q * 4 + rg;
                int n = ng * 16 + m;
                zs[i2 * 32 + n] = f2h(hnew[ng][rg]);     // bounce (plain NHWC)
            }
        __syncthreads();
        // coalesced store of the 4x32x32 tile
        int off = threadIdx.x * 8;                       // 512*8 = 4096 exact
        int px = off >> 5, w = off & 31;
        int pg = (b * PH2 + row0 + (px >> 5) + 2) * PH2 + col0 + (px & 31) + 2;
        u32x4 v = *(const u32x4*)(zs + off);
        *(u32x4*)(Sout + (long)pg * 32 + w) = v;
    }
}

// ---- final: h1 plane -> d_out NCHW fp32 ----
__global__ void final_out(const unsigned short* __restrict__ S1, float* __restrict__ out)
{
    int i = blockIdx.x * 256 + threadIdx.x;    // B*32*HW = 4194304
    if (i >= BB * 32 * HW) return;
    int pix = i & 16383;
    int t = i >> 14;
    int c = t & 31, b = t >> 5;
    int r = pix >> 7, cc = pix & 127;
    long pg = (long)(b * PH2 + r + 2) * PH2 + cc + 2;
    out[i] = h2f(S1[pg * 32 + c]);
}

extern "C" void kernel_launch(void* const* d_in, const int* in_sizes, int n_in,
                              void* d_out, int out_size, void* d_ws, size_t ws_size,
                              hipStream_t stream)
{
    const float* seq = (const float*)d_in[0];
    const float* gw0 = (const float*)d_in[1];
    const float* gb0 = (const float*)d_in[2];
    const float* cw0 = (const float*)d_in[3];
    const float* cb0 = (const float*)d_in[4];
    const float* gw1 = (const float*)d_in[5];
    const float* gb1 = (const float*)d_in[6];
    const float* cw1 = (const float*)d_in[7];
    const float* cb1 = (const float*)d_in[8];
    float* out = (float*)d_out;

    const size_t PL = (size_t)BB * PH2 * PH2 * 32;   // 4,596,736 fp16 / plane

    char* p = (char*)d_ws;
    unsigned short* S0a = (unsigned short*)p; p += PL * 2;
    unsigned short* S0b = (unsigned short*)p; p += PL * 2;
    unsigned short* S1a = (unsigned short*)p; p += PL * 2;
    unsigned short* S1b = (unsigned short*)p; p += PL * 2;
    unsigned short* WG0 = (unsigned short*)p; p += 20480 * 2;
    unsigned short* WC0 = (unsigned short*)p; p += 10240 * 2;
    unsigned short* WG1 = (unsigned short*)p; p += 36864 * 2;
    unsigned short* WC1 = (unsigned short*)p; p += 18432 * 2;

    // zero all 4 planes (states + 2-px halos must be 0; harness poisons ws)
    hipMemsetAsync(S0a, 0, 4 * PL * 2, stream);

    prep_w<<<(10 * 64 * 32 + 255) / 256, 256, 0, stream>>>(gw0, WG0, 64, 33, 10, 1);
    prep_w<<<(10 * 32 * 32 + 255) / 256, 256, 0, stream>>>(cw0, WC0, 32, 33, 10, 1);
    prep_w<<<(18 * 64 * 32 + 255) / 256, 256, 0, stream>>>(gw1, WG1, 64, 64, 18, 0);
    prep_w<<<(18 * 32 * 32 + 255) / 256, 256, 0, stream>>>(cw1, WC1, 32, 64, 18, 0);

    dim3 grid(128, BB), block(512);
    const long xbs = (long)TT * HW;
    unsigned short *h0r = S0a, *h0w = S0b, *h1r = S1a, *h1w = S1b;
    for (int t = 0; t < TT; ++t) {
        const float* xt = seq + (long)t * HW;
        cell_kernel<0><<<grid, block, 0, stream>>>(h0r, h0r, h0w, xt, xbs, WG0, WC0, gb0, cb0);
        cell_kernel<1><<<grid, block, 0, stream>>>(h0w, h1r, h1w, xt, xbs, WG1, WC1, gb1, cb1);
        unsigned short* tmp;
        tmp = h0r; h0r = h0w; h0w = tmp;
        tmp = h1r; h1r = h1w; h1w = tmp;
    }
    final_out<<<(BB * 32 * HW + 255) / 256, 256, 0, stream>>>(h1r, out);
}